// Round 1
// baseline (155.716 us; speedup 1.0000x reference)
//
#include <hip/hip_runtime.h>
#include <hip/hip_bf16.h>

// MultiHeadAttentionNoBatch: T=2048, D_IN=1024, D_OUT=1024, H=16, Dh=64, fp32 in/out.
// Pipeline: split(x,W)->bf16 hi/lo; 3x MFMA split-GEMM (QKV proj); flash attention.
// NOTE: reference multiplies scores by sqrt(Dh)=8 (source quirk) -> folded into exp2 scale.

typedef __bf16 bf16x8 __attribute__((ext_vector_type(8)));
typedef __bf16 bf16x4 __attribute__((ext_vector_type(4)));
typedef float  f32x4  __attribute__((ext_vector_type(4)));

#define MFMA(a, b, c) __builtin_amdgcn_mfma_f32_16x16x32_bf16((a), (b), (c), 0, 0, 0)

#if __has_builtin(__builtin_amdgcn_exp2f)
#define EXP2F(x) __builtin_amdgcn_exp2f(x)
#else
#define EXP2F(x) exp2f(x)
#endif

constexpr int T = 2048, DIN = 1024, DOUT = 1024, NH = 16, DH = 64;
constexpr float SC = 11.5415603f;  // 8 * log2(e): scores scaled by sqrt(Dh)=8

// workspace layout (bytes); total 40 MiB
constexpr size_t SZ_XMAT = (size_t)T * DIN * 2;     // 4 MiB (bf16 2048x1024)
constexpr size_t SZ_WMAT = (size_t)DOUT * DIN * 2;  // 2 MiB
constexpr size_t OFF_XH = 0;
constexpr size_t OFF_XL = OFF_XH + SZ_XMAT;
constexpr size_t OFF_QH = OFF_XL + SZ_XMAT;
constexpr size_t OFF_QL = OFF_QH + SZ_XMAT;
constexpr size_t OFF_KH = OFF_QL + SZ_XMAT;
constexpr size_t OFF_KL = OFF_KH + SZ_XMAT;
constexpr size_t OFF_VT = OFF_KL + SZ_XMAT;         // V^T bf16 [1024][2048]
constexpr size_t OFF_W  = OFF_VT + SZ_XMAT;         // 3 x (W_hi 2MiB, W_lo 2MiB)

__device__ __forceinline__ void gload_lds16(const void* g, void* l) {
  __builtin_amdgcn_global_load_lds(
      (const __attribute__((address_space(1))) void*)g,
      (__attribute__((address_space(3))) void*)l, 16, 0, 0);
}

// ---------------- split fp32 -> bf16 hi + bf16 lo ----------------
__global__ void split_kernel(const float* __restrict__ in, __bf16* __restrict__ hi,
                             __bf16* __restrict__ lo, int n4) {
  const int i = blockIdx.x * blockDim.x + threadIdx.x;
  if (i >= n4) return;
  const f32x4 v = ((const f32x4*)in)[i];
  bf16x4 h, l;
#pragma unroll
  for (int j = 0; j < 4; ++j) {
    const float x = v[j];
    const __bf16 hh = (__bf16)x;
    h[j] = hh;
    l[j] = (__bf16)(x - (float)hh);
  }
  ((bf16x4*)hi)[i] = h;
  ((bf16x4*)lo)[i] = l;
}

// ---------------- QKV projection: out = x @ W^T, bf16x3 split ----------------
// 128x128 tile, BK=32, 4 waves (2x2), each wave 64x64 (4x4 of 16x16x32 MFMA).
// LDS layout per array: [kc(4)][row(128)][8] so global_load_lds dest is linear
// and fragment ds_read_b128 (consecutive rows -> consecutive 16B) is conflict-free.
__global__ __launch_bounds__(256, 2) void qkv_proj(char* ws) {
  const int z = blockIdx.z;  // 0=Q, 1=K, 2=V
  const __bf16* Ah = (const __bf16*)(ws + OFF_XH);
  const __bf16* Al = (const __bf16*)(ws + OFF_XL);
  const __bf16* Bh = (const __bf16*)(ws + OFF_W + (size_t)z * 2 * SZ_WMAT);
  const __bf16* Bl = (const __bf16*)(ws + OFF_W + (size_t)z * 2 * SZ_WMAT + SZ_WMAT);
  const int tm = blockIdx.x * 128;  // 16 tiles over T
  const int tn = blockIdx.y * 128;  // 8 tiles over DOUT
  const int tid = threadIdx.x;
  const int lane = tid & 63, wv = tid >> 6;
  const int wm = wv >> 1, wn = wv & 1;
  const int q4 = lane >> 4, r16 = lane & 15;

  // staging: 4 arrays x 4096 bf16 = 32 KiB; epilogue transpose reuses as [128][136]
  __shared__ alignas(16) __bf16 lds[17408];
  __bf16* ldsAh = lds;
  __bf16* ldsAl = lds + 4096;
  __bf16* ldsBh = lds + 8192;
  __bf16* ldsBl = lds + 12288;

  f32x4 acc[4][4] = {};

  for (int ks = 0; ks < DIN / 32; ++ks) {
    const int k0 = ks * 32;
    __syncthreads();  // previous iteration's LDS reads complete
#pragma unroll
    for (int j = 0; j < 2; ++j) {
      const int cbase = wv * 128 + j * 64;  // wave-uniform chunk base
      const int cidx = cbase + lane;        // chunk = kc*128 + row
      const int row = cidx & 127, kc = cidx >> 7;
      const size_t ga = (size_t)(tm + row) * DIN + k0 + kc * 8;
      const size_t gb = (size_t)(tn + row) * DIN + k0 + kc * 8;
      gload_lds16(Ah + ga, ldsAh + (size_t)cbase * 8);
      gload_lds16(Al + ga, ldsAl + (size_t)cbase * 8);
      gload_lds16(Bh + gb, ldsBh + (size_t)cbase * 8);
      gload_lds16(Bl + gb, ldsBl + (size_t)cbase * 8);
    }
    __syncthreads();  // drains vmcnt (async global->LDS) + visibility

    bf16x8 fah[4], fal[4], fbh[4], fbl[4];
#pragma unroll
    for (int b = 0; b < 4; ++b) {
      const int ra = wm * 64 + b * 16 + r16;
      const int rb = wn * 64 + b * 16 + r16;
      fah[b] = *(const bf16x8*)(ldsAh + ((size_t)q4 * 128 + ra) * 8);
      fal[b] = *(const bf16x8*)(ldsAl + ((size_t)q4 * 128 + ra) * 8);
      fbh[b] = *(const bf16x8*)(ldsBh + ((size_t)q4 * 128 + rb) * 8);
      fbl[b] = *(const bf16x8*)(ldsBl + ((size_t)q4 * 128 + rb) * 8);
    }
#pragma unroll
    for (int bm = 0; bm < 4; ++bm)
#pragma unroll
      for (int bn = 0; bn < 4; ++bn) {
        acc[bm][bn] = MFMA(fah[bm], fbh[bn], acc[bm][bn]);  // hi*hi
        acc[bm][bn] = MFMA(fah[bm], fbl[bn], acc[bm][bn]);  // hi*lo
        acc[bm][bn] = MFMA(fal[bm], fbh[bn], acc[bm][bn]);  // lo*hi
      }
  }

  if (z < 2) {
    // Q/K: re-split fp32 accumulator into bf16 hi/lo for exact QK^T later
    __bf16* Oh = (__bf16*)(ws + (z == 0 ? OFF_QH : OFF_KH));
    __bf16* Ol = (__bf16*)(ws + (z == 0 ? OFF_QL : OFF_KL));
#pragma unroll
    for (int bm = 0; bm < 4; ++bm)
#pragma unroll
      for (int bn = 0; bn < 4; ++bn)
#pragma unroll
        for (int r = 0; r < 4; ++r) {
          const int t = tm + wm * 64 + bm * 16 + q4 * 4 + r;  // D: row=(l>>4)*4+r
          const int n = tn + wn * 64 + bn * 16 + r16;         // D: col=l&15
          const float v = acc[bm][bn][r];
          const __bf16 hh = (__bf16)v;
          Oh[(size_t)t * DOUT + n] = hh;
          Ol[(size_t)t * DOUT + n] = (__bf16)(v - (float)hh);
        }
  } else {
    // V: transpose through LDS, store V^T[1024][2048] bf16 with coalesced b128s
    __syncthreads();
    __bf16* tb = lds;  // [128][136] pad: 272B row stride -> 16B-aligned, 2-way banks
#pragma unroll
    for (int bm = 0; bm < 4; ++bm)
#pragma unroll
      for (int bn = 0; bn < 4; ++bn)
#pragma unroll
        for (int r = 0; r < 4; ++r) {
          const int tl = wm * 64 + bm * 16 + q4 * 4 + r;
          const int nl = wn * 64 + bn * 16 + r16;
          tb[(size_t)nl * 136 + tl] = (__bf16)acc[bm][bn][r];
        }
    __syncthreads();
    __bf16* Vt = (__bf16*)(ws + OFF_VT);
#pragma unroll
    for (int it = 0; it < 8; ++it) {
      const int cid = it * 256 + tid;       // 2048 chunks of 8 elems
      const int nl = cid >> 4, tc = cid & 15;
      const bf16x8 vd = *(const bf16x8*)(tb + (size_t)nl * 136 + tc * 8);
      *(bf16x8*)(Vt + (size_t)(tn + nl) * T + tm + tc * 8) = vd;
    }
  }
}

// ---------------- flash attention ----------------
// block = (head h, q-tile of 64 rows); 4 waves x 16 q-rows; kv-tiles of 64.
// S = (Qh+Ql)(Kh+Kl)^T via 3-term MFMA; online softmax (scale 8 in exponent);
// P -> wave-private LDS (layout swap D->A); PV with V^T staged in LDS.
__global__ __launch_bounds__(256, 2) void attn_kernel(const char* __restrict__ ws,
                                                      float* __restrict__ out) {
  const int bid = blockIdx.x;
  const int h = bid & 15;
  const int qt = 31 - (bid >> 4);  // long tiles scheduled first
  const int tid = threadIdx.x;
  const int lane = tid & 63, wid = tid >> 6;
  const int q4 = lane >> 4, r16 = lane & 15;

  const __bf16* Qh = (const __bf16*)(ws + OFF_QH);
  const __bf16* Ql = (const __bf16*)(ws + OFF_QL);
  const __bf16* Kh = (const __bf16*)(ws + OFF_KH);
  const __bf16* Kl = (const __bf16*)(ws + OFF_KL);
  const __bf16* Vt = (const __bf16*)(ws + OFF_VT);

  __shared__ alignas(16) __bf16 sKh[64 * 72];   // +8 pad: 144B stride, 2-way banks
  __shared__ alignas(16) __bf16 sKl[64 * 72];
  __shared__ alignas(16) __bf16 sVt[64 * 72];   // [d][kv]
  __shared__ alignas(16) __bf16 sP[4][16 * 72]; // wave-private P tile

  // Q fragments held in registers for the whole block
  bf16x8 fqh[2], fql[2];
  {
    const int trow = qt * 64 + wid * 16 + r16;  // A: row = l&15
#pragma unroll
    for (int c = 0; c < 2; ++c) {
      const size_t off = (size_t)trow * DOUT + h * 64 + c * 32 + q4 * 8;
      fqh[c] = *(const bf16x8*)(Qh + off);
      fql[c] = *(const bf16x8*)(Ql + off);
    }
  }

  f32x4 accO[4] = {};
  float mrun[4], lrun[4];
#pragma unroll
  for (int r = 0; r < 4; ++r) { mrun[r] = -1e30f; lrun[r] = 0.f; }

  for (int kvt = 0; kvt <= qt; ++kvt) {
    const int kv0 = kvt * 64;
    __syncthreads();  // previous tile's LDS reads done
#pragma unroll
    for (int j = 0; j < 2; ++j) {
      const int cid = j * 256 + tid;  // 512 chunks per array
      const int row = cid >> 3, dc = cid & 7;
      const size_t koff = (size_t)(kv0 + row) * DOUT + h * 64 + dc * 8;
      const bf16x8 a = *(const bf16x8*)(Kh + koff);
      const bf16x8 b = *(const bf16x8*)(Kl + koff);
      const bf16x8 v = *(const bf16x8*)(Vt + (size_t)(h * 64 + row) * T + kv0 + dc * 8);
      *(bf16x8*)(sKh + (size_t)row * 72 + dc * 8) = a;
      *(bf16x8*)(sKl + (size_t)row * 72 + dc * 8) = b;
      *(bf16x8*)(sVt + (size_t)row * 72 + dc * 8) = v;
    }
    __syncthreads();

    // S = Q K^T (per-wave 16 x 64), 3-term split
    f32x4 s[4] = {};
#pragma unroll
    for (int blk = 0; blk < 4; ++blk) {
#pragma unroll
      for (int c = 0; c < 2; ++c) {
        const size_t ko = ((size_t)(blk * 16 + r16)) * 72 + c * 32 + q4 * 8;  // B: col=l&15
        const bf16x8 kh = *(const bf16x8*)(sKh + ko);
        const bf16x8 kl = *(const bf16x8*)(sKl + ko);
        s[blk] = MFMA(fqh[c], kh, s[blk]);
        s[blk] = MFMA(fqh[c], kl, s[blk]);
        s[blk] = MFMA(fql[c], kh, s[blk]);
      }
    }

    if (kvt == qt) {  // diagonal tile: causal mask
#pragma unroll
      for (int blk = 0; blk < 4; ++blk)
#pragma unroll
        for (int r = 0; r < 4; ++r) {
          const int col = kv0 + blk * 16 + r16;
          const int rowq = qt * 64 + wid * 16 + q4 * 4 + r;
          if (col > rowq) s[blk][r] = -1e30f;
        }
    }

    // online softmax; row r lives on 16 lanes sharing q4, reduce via shfl_xor
#pragma unroll
    for (int r = 0; r < 4; ++r) {
      float mx = fmaxf(fmaxf(s[0][r], s[1][r]), fmaxf(s[2][r], s[3][r]));
#pragma unroll
      for (int m = 1; m < 16; m <<= 1) mx = fmaxf(mx, __shfl_xor(mx, m, 64));
      const float mnew = fmaxf(mrun[r], mx);
      const float scale = EXP2F((mrun[r] - mnew) * SC);
      mrun[r] = mnew;
      lrun[r] *= scale;
#pragma unroll
      for (int d = 0; d < 4; ++d) accO[d][r] *= scale;
      float ps = 0.f;
#pragma unroll
      for (int blk = 0; blk < 4; ++blk) {
        const float p = EXP2F((s[blk][r] - mnew) * SC);
        s[blk][r] = p;
        ps += p;
      }
#pragma unroll
      for (int m = 1; m < 16; m <<= 1) ps += __shfl_xor(ps, m, 64);
      lrun[r] += ps;
    }

    // P (D-layout) -> wave-private LDS -> A-layout fragments
#pragma unroll
    for (int blk = 0; blk < 4; ++blk)
#pragma unroll
      for (int r = 0; r < 4; ++r)
        sP[wid][(size_t)(q4 * 4 + r) * 72 + blk * 16 + r16] = (__bf16)s[blk][r];
    asm volatile("s_waitcnt lgkmcnt(0)" ::: "memory");
    __builtin_amdgcn_sched_barrier(0);

#pragma unroll
    for (int c = 0; c < 2; ++c) {
      const bf16x8 pa = *(const bf16x8*)(&sP[wid][(size_t)r16 * 72 + c * 32 + q4 * 8]);
#pragma unroll
      for (int d = 0; d < 4; ++d) {
        const bf16x8 vb = *(const bf16x8*)(sVt + (size_t)(d * 16 + r16) * 72 + c * 32 + q4 * 8);
        accO[d] = MFMA(pa, vb, accO[d]);
      }
    }
  }

#pragma unroll
  for (int d = 0; d < 4; ++d)
#pragma unroll
    for (int r = 0; r < 4; ++r) {
      const int t = qt * 64 + wid * 16 + q4 * 4 + r;
      out[(size_t)t * DOUT + h * 64 + d * 16 + r16] = accO[d][r] / lrun[r];
    }
}

// ---------------- launch ----------------
extern "C" void kernel_launch(void* const* d_in, const int* in_sizes, int n_in,
                              void* d_out, int out_size, void* d_ws, size_t ws_size,
                              hipStream_t stream) {
  const float* x  = (const float*)d_in[0];
  const float* Wq = (const float*)d_in[1];
  const float* Wk = (const float*)d_in[2];
  const float* Wv = (const float*)d_in[3];
  char* ws = (char*)d_ws;

  __bf16* xh = (__bf16*)(ws + OFF_XH);
  __bf16* xl = (__bf16*)(ws + OFF_XL);

  const int nx4 = T * DIN / 4;     // 524288 -> 2048 blocks
  split_kernel<<<nx4 / 256, 256, 0, stream>>>(x, xh, xl, nx4);
  const int nw4 = DOUT * DIN / 4;  // 262144 -> 1024 blocks
  const float* Ws[3] = {Wq, Wk, Wv};
  for (int z = 0; z < 3; ++z) {
    __bf16* wh = (__bf16*)(ws + OFF_W + (size_t)z * 2 * SZ_WMAT);
    __bf16* wl = (__bf16*)(ws + OFF_W + (size_t)z * 2 * SZ_WMAT + SZ_WMAT);
    split_kernel<<<nw4 / 256, 256, 0, stream>>>(Ws[z], wh, wl, nw4);
  }

  qkv_proj<<<dim3(16, 8, 3), 256, 0, stream>>>(ws);
  attn_kernel<<<dim3(512), 256, 0, stream>>>(ws, (float*)d_out);
}

// Round 2
// 124.976 us; speedup vs baseline: 1.2460x; 1.2460x over previous
//
#include <hip/hip_runtime.h>
#include <hip/hip_bf16.h>

// MultiHeadAttentionNoBatch: T=2048, D_IN=1024, D_OUT=1024, H=16, Dh=64, fp32 in/out.
// Pipeline: split(x,W)->bf16 hi/lo; 3x MFMA split-GEMM (QKV proj, dbuf+counted vmcnt);
// flash attention with SWAPPED QK^T (S^T = K Q^T) so softmax is lane-local.
// NOTE: reference multiplies scores by sqrt(Dh)=8 (source quirk) -> folded into exp2 scale.

typedef __bf16 bf16x8 __attribute__((ext_vector_type(8)));
typedef __bf16 bf16x4 __attribute__((ext_vector_type(4)));
typedef __bf16 bf16x2 __attribute__((ext_vector_type(2)));
typedef float  f32x4  __attribute__((ext_vector_type(4)));

#define MFMA(a, b, c) __builtin_amdgcn_mfma_f32_16x16x32_bf16((a), (b), (c), 0, 0, 0)

#if __has_builtin(__builtin_amdgcn_exp2f)
#define EXP2F(x) __builtin_amdgcn_exp2f(x)
#else
#define EXP2F(x) exp2f(x)
#endif

constexpr int T = 2048, DIN = 1024, DOUT = 1024, NH = 16, DH = 64;
constexpr float SC = 11.5415603f;  // 8 * log2(e): scores scaled by sqrt(Dh)=8

// workspace layout (bytes); total 40 MiB
constexpr size_t SZ_XMAT = (size_t)T * DIN * 2;     // 4 MiB (bf16 2048x1024)
constexpr size_t SZ_WMAT = (size_t)DOUT * DIN * 2;  // 2 MiB
constexpr size_t OFF_XH = 0;
constexpr size_t OFF_XL = OFF_XH + SZ_XMAT;
constexpr size_t OFF_QH = OFF_XL + SZ_XMAT;
constexpr size_t OFF_QL = OFF_QH + SZ_XMAT;
constexpr size_t OFF_KH = OFF_QL + SZ_XMAT;
constexpr size_t OFF_KL = OFF_KH + SZ_XMAT;
constexpr size_t OFF_VT = OFF_KL + SZ_XMAT;         // V^T bf16 [1024][2048]
constexpr size_t OFF_W  = OFF_VT + SZ_XMAT;         // 3 x (W_hi 2MiB, W_lo 2MiB)

__device__ __forceinline__ void gload_lds16(const void* g, void* l) {
  __builtin_amdgcn_global_load_lds(
      (const __attribute__((address_space(1))) void*)g,
      (__attribute__((address_space(3))) void*)l, 16, 0, 0);
}

// ---------------- split fp32 -> bf16 hi + bf16 lo ----------------
__global__ void split_kernel(const float* __restrict__ in, __bf16* __restrict__ hi,
                             __bf16* __restrict__ lo, int n4) {
  const int i = blockIdx.x * blockDim.x + threadIdx.x;
  if (i >= n4) return;
  const f32x4 v = ((const f32x4*)in)[i];
  bf16x4 h, l;
#pragma unroll
  for (int j = 0; j < 4; ++j) {
    const float x = v[j];
    const __bf16 hh = (__bf16)x;
    h[j] = hh;
    l[j] = (__bf16)(x - (float)hh);
  }
  ((bf16x4*)hi)[i] = h;
  ((bf16x4*)lo)[i] = l;
}

// ---------------- QKV projection: out = x @ W^T, bf16x3 split ----------------
// 128x128 tile, BK=32, 4 waves (2x2). Double-buffered LDS staging with
// global_load_lds + counted vmcnt(8): next K-step's loads stay in flight
// across the barrier (T3-min recipe) instead of a full vmcnt(0) drain.
__global__ __launch_bounds__(256, 2) void qkv_proj(char* ws) {
  const int z = blockIdx.z;  // 0=Q, 1=K, 2=V
  const __bf16* Ah = (const __bf16*)(ws + OFF_XH);
  const __bf16* Al = (const __bf16*)(ws + OFF_XL);
  const __bf16* Bh = (const __bf16*)(ws + OFF_W + (size_t)z * 2 * SZ_WMAT);
  const __bf16* Bl = (const __bf16*)(ws + OFF_W + (size_t)z * 2 * SZ_WMAT + SZ_WMAT);
  const int tm = blockIdx.x * 128;  // 16 tiles over T
  const int tn = blockIdx.y * 128;  // 8 tiles over DOUT
  const int tid = threadIdx.x;
  const int lane = tid & 63, wv = tid >> 6;
  const int wm = wv >> 1, wn = wv & 1;
  const int q4 = lane >> 4, r16 = lane & 15;

  // 2 buffers x (4 arrays x 4096 bf16) = 64 KiB; epilogue transpose reuses [128][136]
  __shared__ alignas(16) __bf16 lds[32768];

  // stage K-step ks into buffer buf: 8 global_load_lds (width 16) per thread.
  // LDS layout per array: [kc(4)][row(128)][8] -> linear dest = base + lane*16.
  auto STAGE = [&](int ks, int buf) {
    const int k0 = ks * 32;
    __bf16* base = lds + buf * 16384;
#pragma unroll
    for (int j = 0; j < 2; ++j) {
      const int cbase = wv * 128 + j * 64;  // wave-uniform chunk base
      const int cidx = cbase + lane;        // chunk = kc*128 + row
      const int row = cidx & 127, kc = cidx >> 7;
      const size_t ga = (size_t)(tm + row) * DIN + k0 + kc * 8;
      const size_t gb = (size_t)(tn + row) * DIN + k0 + kc * 8;
      gload_lds16(Ah + ga, base + (size_t)cbase * 8);
      gload_lds16(Al + ga, base + 4096 + (size_t)cbase * 8);
      gload_lds16(Bh + gb, base + 8192 + (size_t)cbase * 8);
      gload_lds16(Bl + gb, base + 12288 + (size_t)cbase * 8);
    }
  };

  f32x4 acc[4][4] = {};
  STAGE(0, 0);

#pragma unroll 2
  for (int ks = 0; ks < 32; ++ks) {
    const int cur = ks & 1;
    if (ks < 31) {
      STAGE(ks + 1, cur ^ 1);
      asm volatile("s_waitcnt vmcnt(8)" ::: "memory");  // current buf's 8 loads done
    } else {
      asm volatile("s_waitcnt vmcnt(0)" ::: "memory");
    }
    __builtin_amdgcn_s_barrier();
    __builtin_amdgcn_sched_barrier(0);

    const __bf16* ldsAh = lds + cur * 16384;
    const __bf16* ldsAl = ldsAh + 4096;
    const __bf16* ldsBh = ldsAh + 8192;
    const __bf16* ldsBl = ldsAh + 12288;

    bf16x8 fah[4], fal[4], fbh[4], fbl[4];
#pragma unroll
    for (int b = 0; b < 4; ++b) {
      const int ra = wm * 64 + b * 16 + r16;
      const int rb = wn * 64 + b * 16 + r16;
      fah[b] = *(const bf16x8*)(ldsAh + ((size_t)q4 * 128 + ra) * 8);
      fal[b] = *(const bf16x8*)(ldsAl + ((size_t)q4 * 128 + ra) * 8);
      fbh[b] = *(const bf16x8*)(ldsBh + ((size_t)q4 * 128 + rb) * 8);
      fbl[b] = *(const bf16x8*)(ldsBl + ((size_t)q4 * 128 + rb) * 8);
    }
#pragma unroll
    for (int bm = 0; bm < 4; ++bm)
#pragma unroll
      for (int bn = 0; bn < 4; ++bn) {
        acc[bm][bn] = MFMA(fah[bm], fbh[bn], acc[bm][bn]);  // hi*hi
        acc[bm][bn] = MFMA(fah[bm], fbl[bn], acc[bm][bn]);  // hi*lo
        acc[bm][bn] = MFMA(fal[bm], fbh[bn], acc[bm][bn]);  // lo*hi
      }
    __builtin_amdgcn_sched_barrier(0);
    __builtin_amdgcn_s_barrier();   // protect buf[cur] before next iter overwrites
    __builtin_amdgcn_sched_barrier(0);
  }

  if (z < 2) {
    // Q/K: re-split fp32 accumulator into bf16 hi/lo for exact QK^T later
    __bf16* Oh = (__bf16*)(ws + (z == 0 ? OFF_QH : OFF_KH));
    __bf16* Ol = (__bf16*)(ws + (z == 0 ? OFF_QL : OFF_KL));
#pragma unroll
    for (int bm = 0; bm < 4; ++bm)
#pragma unroll
      for (int bn = 0; bn < 4; ++bn)
#pragma unroll
        for (int r = 0; r < 4; ++r) {
          const int t = tm + wm * 64 + bm * 16 + q4 * 4 + r;  // D: row=(l>>4)*4+r
          const int n = tn + wn * 64 + bn * 16 + r16;         // D: col=l&15
          const float v = acc[bm][bn][r];
          const __bf16 hh = (__bf16)v;
          Oh[(size_t)t * DOUT + n] = hh;
          Ol[(size_t)t * DOUT + n] = (__bf16)(v - (float)hh);
        }
  } else {
    // V: transpose through LDS, store V^T[1024][2048] bf16 with coalesced b128s
    __syncthreads();
    __bf16* tb = lds;  // [128][136] pad
#pragma unroll
    for (int bm = 0; bm < 4; ++bm)
#pragma unroll
      for (int bn = 0; bn < 4; ++bn)
#pragma unroll
        for (int r = 0; r < 4; ++r) {
          const int tl = wm * 64 + bm * 16 + q4 * 4 + r;
          const int nl = wn * 64 + bn * 16 + r16;
          tb[(size_t)nl * 136 + tl] = (__bf16)acc[bm][bn][r];
        }
    __syncthreads();
    __bf16* Vt = (__bf16*)(ws + OFF_VT);
#pragma unroll
    for (int it = 0; it < 8; ++it) {
      const int cid = it * 256 + tid;       // 2048 chunks of 8 elems
      const int nl = cid >> 4, tc = cid & 15;
      const bf16x8 vd = *(const bf16x8*)(tb + (size_t)nl * 136 + tc * 8);
      *(bf16x8*)(Vt + (size_t)(tn + nl) * T + tm + tc * 8) = vd;
    }
  }
}

// ---------------- flash attention (swapped QK^T) ----------------
// block = (head h, q-tile of 64 rows); 4 waves x 16 q-rows; kv-tiles of 64.
// S^T = (Kh+Kl)(Qh+Ql)^T via 3-term MFMA: A-frag and B-frag lane maps coincide,
// so LDS reads are unchanged but each lane holds 16 k-values of ONE q = lane&15.
// Softmax: 15 in-lane fmax + 2 shfl; state (m,l) lane-local (x4 dup over q4).
// PV swapped too: O^T = V^T P, D col = own q -> rescale is lane-local.
__global__ __launch_bounds__(256, 2) void attn_kernel(const char* __restrict__ ws,
                                                      float* __restrict__ out) {
  const int bid = blockIdx.x;
  const int h = bid & 15;
  // pairing: blocks c and c+256 (likely co-resident on one CU) get qt summing to 31
  const int qt = (bid < 256) ? (31 - (bid >> 4)) : ((bid - 256) >> 4);
  const int tid = threadIdx.x;
  const int lane = tid & 63, wid = tid >> 6;
  const int q4 = lane >> 4, r16 = lane & 15;

  const __bf16* Qh = (const __bf16*)(ws + OFF_QH);
  const __bf16* Ql = (const __bf16*)(ws + OFF_QL);
  const __bf16* Kh = (const __bf16*)(ws + OFF_KH);
  const __bf16* Kl = (const __bf16*)(ws + OFF_KL);
  const __bf16* Vt = (const __bf16*)(ws + OFF_VT);

  __shared__ alignas(16) __bf16 sKh[64 * 72];   // +8 pad
  __shared__ alignas(16) __bf16 sKl[64 * 72];
  __shared__ alignas(16) __bf16 sVt[64 * 72];   // [d][kv]
  __shared__ alignas(16) __bf16 sP[4][16 * 72]; // wave-private P [q][k]

  const int qbase = qt * 64 + wid * 16;
  const int qg = qbase + r16;  // this lane's q row

  // Q B-frags held in registers for the whole block (B: col=l&15=q, row=(l>>4)*8+j=d)
  bf16x8 fqh[2], fql[2];
#pragma unroll
  for (int c = 0; c < 2; ++c) {
    const size_t off = (size_t)qg * DOUT + h * 64 + c * 32 + q4 * 8;
    fqh[c] = *(const bf16x8*)(Qh + off);
    fql[c] = *(const bf16x8*)(Ql + off);
  }

  // staging registers (T14: issue early, write after next barrier)
  bf16x8 st[6];
  const int srow0 = tid >> 3, sdc = tid & 7;   // j=0 chunk
  const int srow1 = 32 + srow0;                // j=1 chunk
  auto ISSUE = [&](int kvt) {
    const int kv0 = kvt * 64;
    const size_t k0 = (size_t)(kv0 + srow0) * DOUT + h * 64 + sdc * 8;
    const size_t k1 = (size_t)(kv0 + srow1) * DOUT + h * 64 + sdc * 8;
    st[0] = *(const bf16x8*)(Kh + k0);
    st[1] = *(const bf16x8*)(Kl + k0);
    st[2] = *(const bf16x8*)(Vt + (size_t)(h * 64 + srow0) * T + kv0 + sdc * 8);
    st[3] = *(const bf16x8*)(Kh + k1);
    st[4] = *(const bf16x8*)(Kl + k1);
    st[5] = *(const bf16x8*)(Vt + (size_t)(h * 64 + srow1) * T + kv0 + sdc * 8);
  };

  f32x4 accT[4] = {};          // O^T: accT[dblk][r] = O[q=qg][d=dblk*16+q4*4+r]
  float mrun = -1e30f, lrun = 0.f;

  ISSUE(0);

  for (int kvt = 0; kvt <= qt; ++kvt) {
    const int kv0 = kvt * 64;
    __syncthreads();  // previous tile's LDS reads done (drains st loads too)
    *(bf16x8*)(sKh + (size_t)srow0 * 72 + sdc * 8) = st[0];
    *(bf16x8*)(sKl + (size_t)srow0 * 72 + sdc * 8) = st[1];
    *(bf16x8*)(sVt + (size_t)srow0 * 72 + sdc * 8) = st[2];
    *(bf16x8*)(sKh + (size_t)srow1 * 72 + sdc * 8) = st[3];
    *(bf16x8*)(sKl + (size_t)srow1 * 72 + sdc * 8) = st[4];
    *(bf16x8*)(sVt + (size_t)srow1 * 72 + sdc * 8) = st[5];
    __syncthreads();  // LDS visible

    if (kvt < qt) ISSUE(kvt + 1);  // overlap next tile's HBM/L2 latency with compute

    // S^T = K Q^T, per-wave 64k x 16q; on diagonal tile skip fully-masked k-blocks
    const int nb = (kvt == qt) ? (wid + 1) : 4;
    f32x4 s[4];
#pragma unroll
    for (int blk = 0; blk < 4; ++blk) {
      if (blk < nb) {
        f32x4 a = {};
#pragma unroll
        for (int c = 0; c < 2; ++c) {
          const size_t ko = ((size_t)(blk * 16 + r16)) * 72 + c * 32 + q4 * 8;
          const bf16x8 kh = *(const bf16x8*)(sKh + ko);
          const bf16x8 kl = *(const bf16x8*)(sKl + ko);
          a = MFMA(kh, fqh[c], a);
          a = MFMA(kl, fqh[c], a);
          a = MFMA(kh, fql[c], a);
        }
        s[blk] = a;
      } else {
        s[blk] = f32x4{-1e30f, -1e30f, -1e30f, -1e30f};
      }
    }

    if (kvt == qt) {  // element-wise causal mask: k > q
#pragma unroll
      for (int blk = 0; blk < 4; ++blk)
#pragma unroll
        for (int r = 0; r < 4; ++r) {
          const int k = kv0 + blk * 16 + q4 * 4 + r;
          if (k > qg) s[blk][r] = -1e30f;
        }
    }

    // lane-local online softmax for q=qg (duplicated across 4 q4 lanes)
    const float m0 = fmaxf(fmaxf(s[0][0], s[0][1]), fmaxf(s[0][2], s[0][3]));
    const float m1 = fmaxf(fmaxf(s[1][0], s[1][1]), fmaxf(s[1][2], s[1][3]));
    const float m2 = fmaxf(fmaxf(s[2][0], s[2][1]), fmaxf(s[2][2], s[2][3]));
    const float m3 = fmaxf(fmaxf(s[3][0], s[3][1]), fmaxf(s[3][2], s[3][3]));
    float mx = fmaxf(fmaxf(m0, m1), fmaxf(m2, m3));
    mx = fmaxf(mx, __shfl_xor(mx, 16, 64));
    mx = fmaxf(mx, __shfl_xor(mx, 32, 64));
    const float mnew = fmaxf(mrun, mx);
    const float scale = EXP2F((mrun - mnew) * SC);
    const float mn2 = mnew * SC;
    mrun = mnew;

    float ps = 0.f;
#pragma unroll
    for (int blk = 0; blk < 4; ++blk)
#pragma unroll
      for (int rp = 0; rp < 2; ++rp) {
        const float p0 = EXP2F(__builtin_fmaf(s[blk][2 * rp], SC, -mn2));
        const float p1 = EXP2F(__builtin_fmaf(s[blk][2 * rp + 1], SC, -mn2));
        ps += p0 + p1;
        bf16x2 w;
        w[0] = (__bf16)p0;
        w[1] = (__bf16)p1;
        // P[q=r16][k = blk*16 + q4*4 + 2rp] packed pair -> ds_write_b32
        *(bf16x2*)(&sP[wid][(size_t)r16 * 72 + blk * 16 + q4 * 4 + 2 * rp]) = w;
      }
    ps += __shfl_xor(ps, 16, 64);
    ps += __shfl_xor(ps, 32, 64);
    lrun = lrun * scale + ps;
#pragma unroll
    for (int d = 0; d < 4; ++d) accT[d] *= scale;

    asm volatile("s_waitcnt lgkmcnt(0)" ::: "memory");
    __builtin_amdgcn_sched_barrier(0);

    // O^T += V^T P : A = V^T rows (row=l&15=d), B = P (col=l&15=q, row=k)
#pragma unroll
    for (int c = 0; c < 2; ++c) {
      const bf16x8 pb = *(const bf16x8*)(&sP[wid][(size_t)r16 * 72 + c * 32 + q4 * 8]);
#pragma unroll
      for (int d = 0; d < 4; ++d) {
        const bf16x8 va = *(const bf16x8*)(sVt + (size_t)(d * 16 + r16) * 72 + c * 32 + q4 * 8);
        accT[d] = MFMA(va, pb, accT[d]);
      }
    }
  }

  const float rl = 1.0f / lrun;
#pragma unroll
  for (int d = 0; d < 4; ++d)
#pragma unroll
    for (int r = 0; r < 4; ++r)
      out[(size_t)qg * DOUT + h * 64 + d * 16 + q4 * 4 + r] = accT[d][r] * rl;
}

// ---------------- launch ----------------
extern "C" void kernel_launch(void* const* d_in, const int* in_sizes, int n_in,
                              void* d_out, int out_size, void* d_ws, size_t ws_size,
                              hipStream_t stream) {
  const float* x  = (const float*)d_in[0];
  const float* Wq = (const float*)d_in[1];
  const float* Wk = (const float*)d_in[2];
  const float* Wv = (const float*)d_in[3];
  char* ws = (char*)d_ws;

  __bf16* xh = (__bf16*)(ws + OFF_XH);
  __bf16* xl = (__bf16*)(ws + OFF_XL);

  const int nx4 = T * DIN / 4;     // 524288 -> 2048 blocks
  split_kernel<<<nx4 / 256, 256, 0, stream>>>(x, xh, xl, nx4);
  const int nw4 = DOUT * DIN / 4;  // 262144 -> 1024 blocks
  const float* Ws[3] = {Wq, Wk, Wv};
  for (int z = 0; z < 3; ++z) {
    __bf16* wh = (__bf16*)(ws + OFF_W + (size_t)z * 2 * SZ_WMAT);
    __bf16* wl = (__bf16*)(ws + OFF_W + (size_t)z * 2 * SZ_WMAT + SZ_WMAT);
    split_kernel<<<nw4 / 256, 256, 0, stream>>>(Ws[z], wh, wl, nw4);
  }

  qkv_proj<<<dim3(16, 8, 3), 256, 0, stream>>>(ws);
  attn_kernel<<<dim3(512), 256, 0, stream>>>(ws, (float*)d_out);
}

// Round 3
// 105.218 us; speedup vs baseline: 1.4799x; 1.1878x over previous
//
#include <hip/hip_runtime.h>
#include <hip/hip_bf16.h>

// MultiHeadAttentionNoBatch: T=2048, D_IN=1024, D_OUT=1024, H=16, Dh=64, fp32 in/out.
// split(x,W)->bf16 hi/lo (one kernel); qkv_proj: Q/K 3-term bf16 split GEMM with
// 3-deep global_load_lds pipeline (96KB LDS, 1 block/CU, grid 256 QK + 128 V),
// V single-term; flash attention: swapped QK^T, dbuf K/V LDS, 1 barrier/tile.
// NOTE: reference multiplies scores by sqrt(Dh)=8 -> folded into exp2 scale.

typedef __bf16 bf16x8 __attribute__((ext_vector_type(8)));
typedef __bf16 bf16x4 __attribute__((ext_vector_type(4)));
typedef __bf16 bf16x2 __attribute__((ext_vector_type(2)));
typedef float  f32x4  __attribute__((ext_vector_type(4)));

#define MFMA(a, b, c) __builtin_amdgcn_mfma_f32_16x16x32_bf16((a), (b), (c), 0, 0, 0)

#if __has_builtin(__builtin_amdgcn_exp2f)
#define EXP2F(x) __builtin_amdgcn_exp2f(x)
#else
#define EXP2F(x) exp2f(x)
#endif

constexpr int T = 2048, DIN = 1024, DOUT = 1024, NH = 16, DH = 64;
constexpr float SC = 11.5415603f;  // 8 * log2(e): scores scaled by sqrt(Dh)=8

// workspace layout (bytes); total 40 MiB
constexpr size_t SZ_XMAT = (size_t)T * DIN * 2;     // 4 MiB
constexpr size_t SZ_WMAT = (size_t)DOUT * DIN * 2;  // 2 MiB
constexpr size_t OFF_XH = 0;
constexpr size_t OFF_XL = OFF_XH + SZ_XMAT;
constexpr size_t OFF_QH = OFF_XL + SZ_XMAT;
constexpr size_t OFF_QL = OFF_QH + SZ_XMAT;
constexpr size_t OFF_KH = OFF_QL + SZ_XMAT;
constexpr size_t OFF_KL = OFF_KH + SZ_XMAT;
constexpr size_t OFF_VT = OFF_KL + SZ_XMAT;         // V^T bf16 [1024][2048]
constexpr size_t OFF_W  = OFF_VT + SZ_XMAT;         // 3 x (W_hi, W_lo)

__device__ __forceinline__ void gload_lds16(const void* g, void* l) {
  __builtin_amdgcn_global_load_lds(
      (const __attribute__((address_space(1))) void*)g,
      (__attribute__((address_space(3))) void*)l, 16, 0, 0);
}

// ---------------- split fp32 -> bf16 hi + bf16 lo (x and 3 W in one launch) ----
__global__ void split_all(const float* __restrict__ x, const float* __restrict__ wq,
                          const float* __restrict__ wk, const float* __restrict__ wv,
                          char* __restrict__ ws) {
  const int i = blockIdx.x * 256 + threadIdx.x;
  const float* src;
  __bf16 *hi, *lo;
  int off;
  if (i < T * DIN / 4) {  // 524288 f32x4 groups of x
    src = x; off = i;
    hi = (__bf16*)(ws + OFF_XH);
    lo = (__bf16*)(ws + OFF_XL);
  } else {
    const int j = i - T * DIN / 4;
    const int z = j >> 18;          // DOUT*DIN/4 = 262144 = 2^18
    off = j & 262143;
    src = (z == 0) ? wq : ((z == 1) ? wk : wv);
    hi = (__bf16*)(ws + OFF_W + (size_t)z * 2 * SZ_WMAT);
    lo = hi + (size_t)DOUT * DIN;
  }
  const f32x4 v = ((const f32x4*)src)[off];
  bf16x4 h, l;
#pragma unroll
  for (int j = 0; j < 4; ++j) {
    const float xv = v[j];
    const __bf16 hh = (__bf16)xv;
    h[j] = hh;
    l[j] = (__bf16)(xv - (float)hh);
  }
  ((bf16x4*)hi)[off] = h;
  ((bf16x4*)lo)[off] = l;
}

// ---------------- QKV projection main loop ----------------
// 128x128 tile, BK=32, 4 waves (2x2), 3-deep global_load_lds pipeline.
// SPLIT=true: Q/K, 4 arrays (Ah,Al,Bh,Bl), 3 MFMA terms, 8 loads/step, buf=32KB.
// SPLIT=false: V, 2 arrays (Ah,Bh), 1 term, 4 loads/step, buf=16KB.
template <bool SPLIT>
__device__ __forceinline__ void proj_loop(const __bf16* __restrict__ Ah,
                                          const __bf16* __restrict__ Al,
                                          const __bf16* __restrict__ Bh,
                                          const __bf16* __restrict__ Bl,
                                          __bf16* lds, int tm, int tn, int lane,
                                          int wv, f32x4 (&acc)[4][4]) {
  constexpr int BUF = SPLIT ? 16384 : 8192;   // elems per buffer
  constexpr int BOFF = SPLIT ? 8192 : 4096;   // B-array offset within buffer
  const int wm = wv >> 1, wn = wv & 1;
  const int q4 = lane >> 4, r16 = lane & 15;

  auto STAGE = [&](int ks, int buf) {
    const int k0 = ks * 32;
    __bf16* base = lds + buf * BUF;
#pragma unroll
    for (int j = 0; j < 2; ++j) {
      const int cbase = wv * 128 + j * 64;  // wave-uniform chunk base
      const int cidx = cbase + lane;        // chunk = kc*128 + row
      const int row = cidx & 127, kc = cidx >> 7;
      const size_t ga = (size_t)(tm + row) * DIN + k0 + kc * 8;
      const size_t gb = (size_t)(tn + row) * DIN + k0 + kc * 8;
      gload_lds16(Ah + ga, base + cbase * 8);
      gload_lds16(Bh + gb, base + BOFF + cbase * 8);
      if constexpr (SPLIT) {
        gload_lds16(Al + ga, base + 4096 + cbase * 8);
        gload_lds16(Bl + gb, base + 12288 + cbase * 8);
      }
    }
  };

  STAGE(0, 0);
  STAGE(1, 1);
  STAGE(2, 2);

  for (int ks = 0; ks < 32; ++ks) {
    const int buf = ks % 3;
    // wait until this step's loads have landed (2 sets stay in flight)
    if (ks < 30) {
      if constexpr (SPLIT) asm volatile("s_waitcnt vmcnt(16)" ::: "memory");
      else                 asm volatile("s_waitcnt vmcnt(8)" ::: "memory");
    } else if (ks == 30) {
      if constexpr (SPLIT) asm volatile("s_waitcnt vmcnt(8)" ::: "memory");
      else                 asm volatile("s_waitcnt vmcnt(4)" ::: "memory");
    } else {
      asm volatile("s_waitcnt vmcnt(0)" ::: "memory");
    }
    __builtin_amdgcn_s_barrier();  // all waves' loads for this buf are done
    __builtin_amdgcn_sched_barrier(0);

    const __bf16* ldsA = lds + buf * BUF;
    const __bf16* ldsB = ldsA + BOFF;

    bf16x8 fah[4], fbh[4], fal[4], fbl[4];
#pragma unroll
    for (int b = 0; b < 4; ++b) {
      const int ra = wm * 64 + b * 16 + r16;
      const int rb = wn * 64 + b * 16 + r16;
      fah[b] = *(const bf16x8*)(ldsA + (q4 * 128 + ra) * 8);
      fbh[b] = *(const bf16x8*)(ldsB + (q4 * 128 + rb) * 8);
      if constexpr (SPLIT) {
        fal[b] = *(const bf16x8*)(ldsA + 4096 + (q4 * 128 + ra) * 8);
        fbl[b] = *(const bf16x8*)(ldsB + 4096 + (q4 * 128 + rb) * 8);
      }
    }
#pragma unroll
    for (int bm = 0; bm < 4; ++bm)
#pragma unroll
      for (int bn = 0; bn < 4; ++bn) {
        acc[bm][bn] = MFMA(fah[bm], fbh[bn], acc[bm][bn]);
        if constexpr (SPLIT) {
          acc[bm][bn] = MFMA(fah[bm], fbl[bn], acc[bm][bn]);
          acc[bm][bn] = MFMA(fal[bm], fbh[bn], acc[bm][bn]);
        }
      }
    asm volatile("s_waitcnt lgkmcnt(0)" ::: "memory");  // reads done
    __builtin_amdgcn_sched_barrier(0);
    __builtin_amdgcn_s_barrier();  // buffer free across all waves
    __builtin_amdgcn_sched_barrier(0);
    if (ks < 29) STAGE(ks + 3, buf);  // refill just-freed buffer
  }
}

// grid: bids 0..127 = Q, 128..255 = K (dispatch first, 1 block/CU via 96KB LDS),
// 256..383 = V (cheap 1-term blocks backfill as CUs free up).
__global__ __launch_bounds__(256, 1) void qkv_proj(char* ws) {
  const int bid = blockIdx.x;
  const int z = bid >> 7;
  const int t_ = bid & 127;
  const int tm = (t_ >> 3) * 128;
  const int tn = (t_ & 7) * 128;
  const int tid = threadIdx.x;
  const int lane = tid & 63, wv = tid >> 6;
  const int wm = wv >> 1, wn = wv & 1;
  const int q4 = lane >> 4, r16 = lane & 15;

  const __bf16* Ah = (const __bf16*)(ws + OFF_XH);
  const __bf16* Al = (const __bf16*)(ws + OFF_XL);
  const __bf16* Bh = (const __bf16*)(ws + OFF_W + (size_t)z * 2 * SZ_WMAT);
  const __bf16* Bl = Bh + (size_t)DOUT * DIN;

  __shared__ alignas(16) __bf16 lds[49152];  // 96 KB -> 1 block/CU

  f32x4 acc[4][4] = {};

  if (z < 2) {
    proj_loop<true>(Ah, Al, Bh, Bl, lds, tm, tn, lane, wv, acc);
    // Q/K: re-split fp32 accumulator into bf16 hi/lo for exact QK^T later
    __bf16* Oh = (__bf16*)(ws + (z == 0 ? OFF_QH : OFF_KH));
    __bf16* Ol = (__bf16*)(ws + (z == 0 ? OFF_QL : OFF_KL));
#pragma unroll
    for (int bm = 0; bm < 4; ++bm)
#pragma unroll
      for (int bn = 0; bn < 4; ++bn)
#pragma unroll
        for (int r = 0; r < 4; ++r) {
          const int t = tm + wm * 64 + bm * 16 + q4 * 4 + r;  // D: row=(l>>4)*4+r
          const int n = tn + wn * 64 + bn * 16 + r16;         // D: col=l&15
          const float v = acc[bm][bn][r];
          const __bf16 hh = (__bf16)v;
          Oh[(size_t)t * DOUT + n] = hh;
          Ol[(size_t)t * DOUT + n] = (__bf16)(v - (float)hh);
        }
  } else {
    proj_loop<false>(Ah, Al, Bh, Bl, lds, tm, tn, lane, wv, acc);
    // V: transpose through LDS, store V^T[1024][2048] bf16 with coalesced b128s
    __syncthreads();
    __bf16* tb = lds;  // [128][136]
#pragma unroll
    for (int bm = 0; bm < 4; ++bm)
#pragma unroll
      for (int bn = 0; bn < 4; ++bn)
#pragma unroll
        for (int r = 0; r < 4; ++r) {
          const int tl = wm * 64 + bm * 16 + q4 * 4 + r;
          const int nl = wn * 64 + bn * 16 + r16;
          tb[(size_t)nl * 136 + tl] = (__bf16)acc[bm][bn][r];
        }
    __syncthreads();
    __bf16* Vt = (__bf16*)(ws + OFF_VT);
#pragma unroll
    for (int it = 0; it < 8; ++it) {
      const int cid = it * 256 + tid;
      const int nl = cid >> 4, tc = cid & 15;
      const bf16x8 vd = *(const bf16x8*)(tb + (size_t)nl * 136 + tc * 8);
      *(bf16x8*)(Vt + (size_t)(tn + nl) * T + tm + tc * 8) = vd;
    }
  }
}

// ---------------- flash attention (swapped QK^T, dbuf K/V, 1 barrier/tile) ----
__global__ __launch_bounds__(256, 2) void attn_kernel(const char* __restrict__ ws,
                                                      float* __restrict__ out) {
  const int bid = blockIdx.x;
  const int h = bid & 15;
  // pairing: blocks c and c+256 (co-resident) get qt summing to 31
  const int qt = (bid < 256) ? (31 - (bid >> 4)) : ((bid - 256) >> 4);
  const int tid = threadIdx.x;
  const int lane = tid & 63, wid = tid >> 6;
  const int q4 = lane >> 4, r16 = lane & 15;

  const __bf16* Qh = (const __bf16*)(ws + OFF_QH);
  const __bf16* Ql = (const __bf16*)(ws + OFF_QL);
  const __bf16* Kh = (const __bf16*)(ws + OFF_KH);
  const __bf16* Kl = (const __bf16*)(ws + OFF_KL);
  const __bf16* Vt = (const __bf16*)(ws + OFF_VT);

  __shared__ alignas(16) __bf16 sKh[2][64 * 72];  // +8 pad
  __shared__ alignas(16) __bf16 sKl[2][64 * 72];
  __shared__ alignas(16) __bf16 sVt[2][64 * 72];  // [d][kv]
  __shared__ alignas(16) __bf16 sP[4][16 * 72];   // wave-private P [q][k]

  const int qbase = qt * 64 + wid * 16;
  const int qg = qbase + r16;  // this lane's q row

  // Q B-frags held in registers for the whole block
  bf16x8 fqh[2], fql[2];
#pragma unroll
  for (int c = 0; c < 2; ++c) {
    const size_t off = (size_t)qg * DOUT + h * 64 + c * 32 + q4 * 8;
    fqh[c] = *(const bf16x8*)(Qh + off);
    fql[c] = *(const bf16x8*)(Ql + off);
  }

  // staging registers (T14): issue 2 tiles ahead, write 1 tile ahead
  bf16x8 st[6];
  const int srow0 = tid >> 3, sdc = tid & 7;
  const int srow1 = 32 + srow0;
  auto ISSUE = [&](int kvt) {
    const int kv0 = kvt * 64;
    const size_t k0 = (size_t)(kv0 + srow0) * DOUT + h * 64 + sdc * 8;
    const size_t k1 = (size_t)(kv0 + srow1) * DOUT + h * 64 + sdc * 8;
    st[0] = *(const bf16x8*)(Kh + k0);
    st[1] = *(const bf16x8*)(Kl + k0);
    st[2] = *(const bf16x8*)(Vt + (size_t)(h * 64 + srow0) * T + kv0 + sdc * 8);
    st[3] = *(const bf16x8*)(Kh + k1);
    st[4] = *(const bf16x8*)(Kl + k1);
    st[5] = *(const bf16x8*)(Vt + (size_t)(h * 64 + srow1) * T + kv0 + sdc * 8);
  };
  auto WRITE = [&](int b) {
    *(bf16x8*)(&sKh[b][srow0 * 72 + sdc * 8]) = st[0];
    *(bf16x8*)(&sKl[b][srow0 * 72 + sdc * 8]) = st[1];
    *(bf16x8*)(&sVt[b][srow0 * 72 + sdc * 8]) = st[2];
    *(bf16x8*)(&sKh[b][srow1 * 72 + sdc * 8]) = st[3];
    *(bf16x8*)(&sKl[b][srow1 * 72 + sdc * 8]) = st[4];
    *(bf16x8*)(&sVt[b][srow1 * 72 + sdc * 8]) = st[5];
  };

  f32x4 accT[4] = {};  // O^T: accT[dblk][r] = O[q=qg][d=dblk*16+q4*4+r]
  float mrun = -1e30f, lrun = 0.f;

  ISSUE(0);
  asm volatile("s_waitcnt vmcnt(0)" ::: "memory");
  WRITE(0);
  if (qt > 0) ISSUE(1);
  asm volatile("s_waitcnt lgkmcnt(0)" ::: "memory");
  __builtin_amdgcn_s_barrier();
  __builtin_amdgcn_sched_barrier(0);

  for (int kvt = 0; kvt <= qt; ++kvt) {
    const int cur = kvt & 1;
    const int kv0 = kvt * 64;
    // S^T = K Q^T; on diagonal tile skip fully-masked k-blocks
    const int nb = (kvt == qt) ? (wid + 1) : 4;
    f32x4 s[4];
    __builtin_amdgcn_s_setprio(1);
#pragma unroll
    for (int blk = 0; blk < 4; ++blk) {
      if (blk < nb) {
        f32x4 a = {};
#pragma unroll
        for (int c = 0; c < 2; ++c) {
          const int ko = (blk * 16 + r16) * 72 + c * 32 + q4 * 8;
          const bf16x8 kh = *(const bf16x8*)(&sKh[cur][ko]);
          const bf16x8 kl = *(const bf16x8*)(&sKl[cur][ko]);
          a = MFMA(kh, fqh[c], a);
          a = MFMA(kl, fqh[c], a);
          a = MFMA(kh, fql[c], a);
        }
        s[blk] = a;
      } else {
        s[blk] = f32x4{-1e30f, -1e30f, -1e30f, -1e30f};
      }
    }
    __builtin_amdgcn_s_setprio(0);

    if (kvt == qt) {  // element-wise causal mask: k > q
#pragma unroll
      for (int blk = 0; blk < 4; ++blk)
#pragma unroll
        for (int r = 0; r < 4; ++r) {
          const int k = kv0 + blk * 16 + q4 * 4 + r;
          if (k > qg) s[blk][r] = -1e30f;
        }
    }

    // lane-local online softmax for q=qg (duplicated across the 4 q4 lanes)
    const float m0 = fmaxf(fmaxf(s[0][0], s[0][1]), fmaxf(s[0][2], s[0][3]));
    const float m1 = fmaxf(fmaxf(s[1][0], s[1][1]), fmaxf(s[1][2], s[1][3]));
    const float m2 = fmaxf(fmaxf(s[2][0], s[2][1]), fmaxf(s[2][2], s[2][3]));
    const float m3 = fmaxf(fmaxf(s[3][0], s[3][1]), fmaxf(s[3][2], s[3][3]));
    float mx = fmaxf(fmaxf(m0, m1), fmaxf(m2, m3));
    mx = fmaxf(mx, __shfl_xor(mx, 16, 64));
    mx = fmaxf(mx, __shfl_xor(mx, 32, 64));
    const float mnew = fmaxf(mrun, mx);
    const float scale = EXP2F((mrun - mnew) * SC);
    const float mn2 = mnew * SC;
    mrun = mnew;

    float ps = 0.f;
#pragma unroll
    for (int blk = 0; blk < 4; ++blk)
#pragma unroll
      for (int rp = 0; rp < 2; ++rp) {
        const float p0 = EXP2F(__builtin_fmaf(s[blk][2 * rp], SC, -mn2));
        const float p1 = EXP2F(__builtin_fmaf(s[blk][2 * rp + 1], SC, -mn2));
        ps += p0 + p1;
        bf16x2 w;
        w[0] = (__bf16)p0;
        w[1] = (__bf16)p1;
        *(bf16x2*)(&sP[wid][r16 * 72 + blk * 16 + q4 * 4 + 2 * rp]) = w;
      }
    ps += __shfl_xor(ps, 16, 64);
    ps += __shfl_xor(ps, 32, 64);
    lrun = lrun * scale + ps;
#pragma unroll
    for (int d = 0; d < 4; ++d) accT[d] *= scale;

    asm volatile("s_waitcnt lgkmcnt(0)" ::: "memory");  // sP visible to own wave
    __builtin_amdgcn_sched_barrier(0);

    // O^T += V^T P : A = V^T rows (row=l&15=d), B = P (col=l&15=q, row=k)
    __builtin_amdgcn_s_setprio(1);
#pragma unroll
    for (int c = 0; c < 2; ++c) {
      const bf16x8 pb = *(const bf16x8*)(&sP[wid][r16 * 72 + c * 32 + q4 * 8]);
#pragma unroll
      for (int d = 0; d < 4; ++d) {
        const bf16x8 va =
            *(const bf16x8*)(&sVt[cur][(d * 16 + r16) * 72 + c * 32 + q4 * 8]);
        accT[d] = MFMA(va, pb, accT[d]);
      }
    }
    __builtin_amdgcn_s_setprio(0);

    if (kvt < qt) {  // stage tile kvt+1 into the other buffer; refill st
      asm volatile("s_waitcnt vmcnt(0)" ::: "memory");
      WRITE(cur ^ 1);
      if (kvt + 1 < qt) ISSUE(kvt + 2);
    }
    asm volatile("s_waitcnt lgkmcnt(0)" ::: "memory");  // ds reads+writes done
    __builtin_amdgcn_sched_barrier(0);
    __builtin_amdgcn_s_barrier();  // single barrier per tile (no vmcnt drain)
    __builtin_amdgcn_sched_barrier(0);
  }

  const float rl = 1.0f / lrun;
#pragma unroll
  for (int d = 0; d < 4; ++d)
#pragma unroll
    for (int r = 0; r < 4; ++r)
      out[(size_t)qg * DOUT + h * 64 + d * 16 + q4 * 4 + r] = accT[d][r] * rl;
}

// ---------------- launch ----------------
extern "C" void kernel_launch(void* const* d_in, const int* in_sizes, int n_in,
                              void* d_out, int out_size, void* d_ws, size_t ws_size,
                              hipStream_t stream) {
  const float* x  = (const float*)d_in[0];
  const float* Wq = (const float*)d_in[1];
  const float* Wk = (const float*)d_in[2];
  const float* Wv = (const float*)d_in[3];
  char* ws = (char*)d_ws;

  // (T*DIN + 3*DOUT*DIN)/4 elementsx4 = 1310720 -> 5120 blocks
  split_all<<<5120, 256, 0, stream>>>(x, Wq, Wk, Wv, ws);
  qkv_proj<<<384, 256, 0, stream>>>(ws);
  attn_kernel<<<512, 256, 0, stream>>>(ws, (float*)d_out);
}

// Round 4
// 102.476 us; speedup vs baseline: 1.5195x; 1.0268x over previous
//
#include <hip/hip_runtime.h>
#include <hip/hip_bf16.h>

// MultiHeadAttentionNoBatch: T=2048, D_IN=1024, D_OUT=1024, H=16, Dh=64, fp32 in/out.
// split(x,W)->bf16 hi/lo (one kernel); qkv_proj: Q/K 3-term bf16 split GEMM,
// 2-deep global_load_lds pipeline, 64KB LDS -> 2 blocks/CU (grid 256 QK + 128 V
// all co-resident); V single-term. Flash attention: swapped QK^T (lane-local
// softmax), dbuf K/V LDS, 1 barrier/tile, defer-max rescale skip.
// NOTE: reference multiplies scores by sqrt(Dh)=8 -> folded into exp2 scale.

typedef __bf16 bf16x8 __attribute__((ext_vector_type(8)));
typedef __bf16 bf16x4 __attribute__((ext_vector_type(4)));
typedef __bf16 bf16x2 __attribute__((ext_vector_type(2)));
typedef float  f32x4  __attribute__((ext_vector_type(4)));

#define MFMA(a, b, c) __builtin_amdgcn_mfma_f32_16x16x32_bf16((a), (b), (c), 0, 0, 0)

#if __has_builtin(__builtin_amdgcn_exp2f)
#define EXP2F(x) __builtin_amdgcn_exp2f(x)
#else
#define EXP2F(x) exp2f(x)
#endif

constexpr int T = 2048, DIN = 1024, DOUT = 1024, NH = 16, DH = 64;
constexpr float SC = 11.5415603f;   // 8 * log2(e): scores scaled by sqrt(Dh)=8
constexpr float DEFER = 0.6931472f; // 8 exponent-bits / SC: defer-max threshold

// workspace layout (bytes); total 40 MiB
constexpr size_t SZ_XMAT = (size_t)T * DIN * 2;     // 4 MiB
constexpr size_t SZ_WMAT = (size_t)DOUT * DIN * 2;  // 2 MiB
constexpr size_t OFF_XH = 0;
constexpr size_t OFF_XL = OFF_XH + SZ_XMAT;
constexpr size_t OFF_QH = OFF_XL + SZ_XMAT;
constexpr size_t OFF_QL = OFF_QH + SZ_XMAT;
constexpr size_t OFF_KH = OFF_QL + SZ_XMAT;
constexpr size_t OFF_KL = OFF_KH + SZ_XMAT;
constexpr size_t OFF_VT = OFF_KL + SZ_XMAT;         // V^T bf16 [1024][2048]
constexpr size_t OFF_W  = OFF_VT + SZ_XMAT;         // 3 x (W_hi, W_lo)

__device__ __forceinline__ void gload_lds16(const void* g, void* l) {
  __builtin_amdgcn_global_load_lds(
      (const __attribute__((address_space(1))) void*)g,
      (__attribute__((address_space(3))) void*)l, 16, 0, 0);
}

// ---------------- split fp32 -> bf16 hi + bf16 lo (x and 3 W in one launch) ----
__global__ void split_all(const float* __restrict__ x, const float* __restrict__ wq,
                          const float* __restrict__ wk, const float* __restrict__ wv,
                          char* __restrict__ ws) {
  const int i = blockIdx.x * 256 + threadIdx.x;
  const float* src;
  __bf16 *hi, *lo;
  int off;
  if (i < T * DIN / 4) {  // 524288 f32x4 groups of x
    src = x; off = i;
    hi = (__bf16*)(ws + OFF_XH);
    lo = (__bf16*)(ws + OFF_XL);
  } else {
    const int j = i - T * DIN / 4;
    const int z = j >> 18;          // DOUT*DIN/4 = 262144 = 2^18
    off = j & 262143;
    src = (z == 0) ? wq : ((z == 1) ? wk : wv);
    hi = (__bf16*)(ws + OFF_W + (size_t)z * 2 * SZ_WMAT);
    lo = hi + (size_t)DOUT * DIN;
  }
  const f32x4 v = ((const f32x4*)src)[off];
  bf16x4 h, l;
#pragma unroll
  for (int j = 0; j < 4; ++j) {
    const float xv = v[j];
    const __bf16 hh = (__bf16)xv;
    h[j] = hh;
    l[j] = (__bf16)(xv - (float)hh);
  }
  ((bf16x4*)hi)[off] = h;
  ((bf16x4*)lo)[off] = l;
}

// ---------------- QKV projection main loop ----------------
// 128x128 tile, BK=32, 4 waves (2x2), 2-deep global_load_lds pipeline (64KB).
// SPLIT=true: Q/K, 4 arrays, 3 MFMA terms, 8 loads/step/thread.
// SPLIT=false: V, 2 arrays, 1 term, 4 loads/step/thread.
template <bool SPLIT>
__device__ __forceinline__ void proj_loop(const __bf16* __restrict__ Ah,
                                          const __bf16* __restrict__ Al,
                                          const __bf16* __restrict__ Bh,
                                          const __bf16* __restrict__ Bl,
                                          __bf16* lds, int tm, int tn, int lane,
                                          int wv, f32x4 (&acc)[4][4]) {
  constexpr int BUF = SPLIT ? 16384 : 8192;   // elems per buffer
  constexpr int BOFF = SPLIT ? 8192 : 4096;   // B-array offset within buffer
  const int wm = wv >> 1, wn = wv & 1;
  const int q4 = lane >> 4, r16 = lane & 15;

  auto STAGE = [&](int ks, int buf) {
    const int k0 = ks * 32;
    __bf16* base = lds + buf * BUF;
#pragma unroll
    for (int j = 0; j < 2; ++j) {
      const int cbase = wv * 128 + j * 64;  // wave-uniform chunk base
      const int cidx = cbase + lane;        // chunk = kc*128 + row
      const int row = cidx & 127, kc = cidx >> 7;
      const size_t ga = (size_t)(tm + row) * DIN + k0 + kc * 8;
      const size_t gb = (size_t)(tn + row) * DIN + k0 + kc * 8;
      gload_lds16(Ah + ga, base + cbase * 8);
      gload_lds16(Bh + gb, base + BOFF + cbase * 8);
      if constexpr (SPLIT) {
        gload_lds16(Al + ga, base + 4096 + cbase * 8);
        gload_lds16(Bl + gb, base + 12288 + cbase * 8);
      }
    }
  };

  STAGE(0, 0);
  STAGE(1, 1);

  for (int ks = 0; ks < 32; ++ks) {
    const int buf = ks & 1;
    // steady state: 2 sets in flight; wait for current set only (never drain)
    if (ks < 31) {
      if constexpr (SPLIT) asm volatile("s_waitcnt vmcnt(8)" ::: "memory");
      else                 asm volatile("s_waitcnt vmcnt(4)" ::: "memory");
    } else {
      asm volatile("s_waitcnt vmcnt(0)" ::: "memory");
    }
    __builtin_amdgcn_s_barrier();  // all waves' loads for this buf are done
    __builtin_amdgcn_sched_barrier(0);

    const __bf16* ldsA = lds + buf * BUF;
    const __bf16* ldsB = ldsA + BOFF;

    bf16x8 fah[4], fbh[4], fal[4], fbl[4];
#pragma unroll
    for (int b = 0; b < 4; ++b) {
      const int ra = wm * 64 + b * 16 + r16;
      const int rb = wn * 64 + b * 16 + r16;
      fah[b] = *(const bf16x8*)(ldsA + (q4 * 128 + ra) * 8);
      fbh[b] = *(const bf16x8*)(ldsB + (q4 * 128 + rb) * 8);
      if constexpr (SPLIT) {
        fal[b] = *(const bf16x8*)(ldsA + 4096 + (q4 * 128 + ra) * 8);
        fbl[b] = *(const bf16x8*)(ldsB + 4096 + (q4 * 128 + rb) * 8);
      }
    }
    __builtin_amdgcn_s_setprio(1);
#pragma unroll
    for (int bm = 0; bm < 4; ++bm)
#pragma unroll
      for (int bn = 0; bn < 4; ++bn) {
        acc[bm][bn] = MFMA(fah[bm], fbh[bn], acc[bm][bn]);
        if constexpr (SPLIT) {
          acc[bm][bn] = MFMA(fah[bm], fbl[bn], acc[bm][bn]);
          acc[bm][bn] = MFMA(fal[bm], fbh[bn], acc[bm][bn]);
        }
      }
    __builtin_amdgcn_s_setprio(0);
    asm volatile("s_waitcnt lgkmcnt(0)" ::: "memory");  // this wave's reads done
    __builtin_amdgcn_sched_barrier(0);
    __builtin_amdgcn_s_barrier();  // buffer free across all waves
    __builtin_amdgcn_sched_barrier(0);
    if (ks < 30) STAGE(ks + 2, buf);  // refill just-freed buffer
  }
}

// grid: bids 0..127 = Q, 128..255 = K, 256..383 = V. 64KB LDS -> 2 blocks/CU,
// so all 384 blocks are co-resident (<= 512 slots): V overlaps QK, and each
// CU's second block fills the other's latency/barrier stalls.
__global__ __launch_bounds__(256, 2) void qkv_proj(char* ws) {
  const int bid = blockIdx.x;
  const int z = bid >> 7;
  const int t_ = bid & 127;
  const int tm = (t_ >> 3) * 128;
  const int tn = (t_ & 7) * 128;
  const int tid = threadIdx.x;
  const int lane = tid & 63, wv = tid >> 6;
  const int wm = wv >> 1, wn = wv & 1;
  const int q4 = lane >> 4, r16 = lane & 15;

  const __bf16* Ah = (const __bf16*)(ws + OFF_XH);
  const __bf16* Al = (const __bf16*)(ws + OFF_XL);
  const __bf16* Bh = (const __bf16*)(ws + OFF_W + (size_t)z * 2 * SZ_WMAT);
  const __bf16* Bl = Bh + (size_t)DOUT * DIN;

  __shared__ alignas(16) __bf16 lds[32768];  // 64 KB

  f32x4 acc[4][4] = {};

  if (z < 2) {
    proj_loop<true>(Ah, Al, Bh, Bl, lds, tm, tn, lane, wv, acc);
    // Q/K: re-split fp32 accumulator into bf16 hi/lo for exact QK^T later
    __bf16* Oh = (__bf16*)(ws + (z == 0 ? OFF_QH : OFF_KH));
    __bf16* Ol = (__bf16*)(ws + (z == 0 ? OFF_QL : OFF_KL));
#pragma unroll
    for (int bm = 0; bm < 4; ++bm)
#pragma unroll
      for (int bn = 0; bn < 4; ++bn)
#pragma unroll
        for (int r = 0; r < 4; ++r) {
          const int t = tm + wm * 64 + bm * 16 + q4 * 4 + r;  // D: row=(l>>4)*4+r
          const int n = tn + wn * 64 + bn * 16 + r16;         // D: col=l&15
          const float v = acc[bm][bn][r];
          const __bf16 hh = (__bf16)v;
          Oh[(size_t)t * DOUT + n] = hh;
          Ol[(size_t)t * DOUT + n] = (__bf16)(v - (float)hh);
        }
  } else {
    proj_loop<false>(Ah, Al, Bh, Bl, lds, tm, tn, lane, wv, acc);
    // V: transpose through LDS, store V^T[1024][2048] bf16 with coalesced b128s
    __syncthreads();
    __bf16* tb = lds;  // [128][136]
#pragma unroll
    for (int bm = 0; bm < 4; ++bm)
#pragma unroll
      for (int bn = 0; bn < 4; ++bn)
#pragma unroll
        for (int r = 0; r < 4; ++r) {
          const int tl = wm * 64 + bm * 16 + q4 * 4 + r;
          const int nl = wn * 64 + bn * 16 + r16;
          tb[(size_t)nl * 136 + tl] = (__bf16)acc[bm][bn][r];
        }
    __syncthreads();
    __bf16* Vt = (__bf16*)(ws + OFF_VT);
#pragma unroll
    for (int it = 0; it < 8; ++it) {
      const int cid = it * 256 + tid;
      const int nl = cid >> 4, tc = cid & 15;
      const bf16x8 vd = *(const bf16x8*)(tb + (size_t)nl * 136 + tc * 8);
      *(bf16x8*)(Vt + (size_t)(tn + nl) * T + tm + tc * 8) = vd;
    }
  }
}

// ---------------- flash attention (swapped QK^T, dbuf K/V, 1 barrier/tile) ----
__global__ __launch_bounds__(256, 2) void attn_kernel(const char* __restrict__ ws,
                                                      float* __restrict__ out) {
  const int bid = blockIdx.x;
  const int h = bid & 15;
  // pairing: blocks c and c+256 (co-resident) get qt summing to 31
  const int qt = (bid < 256) ? (31 - (bid >> 4)) : ((bid - 256) >> 4);
  const int tid = threadIdx.x;
  const int lane = tid & 63, wid = tid >> 6;
  const int q4 = lane >> 4, r16 = lane & 15;

  const __bf16* Qh = (const __bf16*)(ws + OFF_QH);
  const __bf16* Ql = (const __bf16*)(ws + OFF_QL);
  const __bf16* Kh = (const __bf16*)(ws + OFF_KH);
  const __bf16* Kl = (const __bf16*)(ws + OFF_KL);
  const __bf16* Vt = (const __bf16*)(ws + OFF_VT);

  __shared__ alignas(16) __bf16 sKh[2][64 * 72];  // +8 pad
  __shared__ alignas(16) __bf16 sKl[2][64 * 72];
  __shared__ alignas(16) __bf16 sVt[2][64 * 72];  // [d][kv]
  __shared__ alignas(16) __bf16 sP[4][16 * 72];   // wave-private P [q][k]

  const int qbase = qt * 64 + wid * 16;
  const int qg = qbase + r16;  // this lane's q row

  // Q B-frags held in registers for the whole block
  bf16x8 fqh[2], fql[2];
#pragma unroll
  for (int c = 0; c < 2; ++c) {
    const size_t off = (size_t)qg * DOUT + h * 64 + c * 32 + q4 * 8;
    fqh[c] = *(const bf16x8*)(Qh + off);
    fql[c] = *(const bf16x8*)(Ql + off);
  }

  // staging registers (T14): issue 2 tiles ahead, write 1 tile ahead
  bf16x8 st[6];
  const int srow0 = tid >> 3, sdc = tid & 7;
  const int srow1 = 32 + srow0;
  auto ISSUE = [&](int kvt) {
    const int kv0 = kvt * 64;
    const size_t k0 = (size_t)(kv0 + srow0) * DOUT + h * 64 + sdc * 8;
    const size_t k1 = (size_t)(kv0 + srow1) * DOUT + h * 64 + sdc * 8;
    st[0] = *(const bf16x8*)(Kh + k0);
    st[1] = *(const bf16x8*)(Kl + k0);
    st[2] = *(const bf16x8*)(Vt + (size_t)(h * 64 + srow0) * T + kv0 + sdc * 8);
    st[3] = *(const bf16x8*)(Kh + k1);
    st[4] = *(const bf16x8*)(Kl + k1);
    st[5] = *(const bf16x8*)(Vt + (size_t)(h * 64 + srow1) * T + kv0 + sdc * 8);
  };
  auto WRITE = [&](int b) {
    *(bf16x8*)(&sKh[b][srow0 * 72 + sdc * 8]) = st[0];
    *(bf16x8*)(&sKl[b][srow0 * 72 + sdc * 8]) = st[1];
    *(bf16x8*)(&sVt[b][srow0 * 72 + sdc * 8]) = st[2];
    *(bf16x8*)(&sKh[b][srow1 * 72 + sdc * 8]) = st[3];
    *(bf16x8*)(&sKl[b][srow1 * 72 + sdc * 8]) = st[4];
    *(bf16x8*)(&sVt[b][srow1 * 72 + sdc * 8]) = st[5];
  };

  f32x4 accT[4] = {};  // O^T: accT[dblk][r] = O[q=qg][d=dblk*16+q4*4+r]
  float mrun = -1e30f, lrun = 0.f;

  ISSUE(0);
  asm volatile("s_waitcnt vmcnt(0)" ::: "memory");
  WRITE(0);
  if (qt > 0) ISSUE(1);
  asm volatile("s_waitcnt lgkmcnt(0)" ::: "memory");
  __builtin_amdgcn_s_barrier();
  __builtin_amdgcn_sched_barrier(0);

  for (int kvt = 0; kvt <= qt; ++kvt) {
    const int cur = kvt & 1;
    const int kv0 = kvt * 64;
    // S^T = K Q^T; on diagonal tile skip fully-masked k-blocks
    const int nb = (kvt == qt) ? (wid + 1) : 4;
    f32x4 s[4];
    __builtin_amdgcn_s_setprio(1);
#pragma unroll
    for (int blk = 0; blk < 4; ++blk) {
      if (blk < nb) {
        f32x4 a = {};
#pragma unroll
        for (int c = 0; c < 2; ++c) {
          const int ko = (blk * 16 + r16) * 72 + c * 32 + q4 * 8;
          const bf16x8 kh = *(const bf16x8*)(&sKh[cur][ko]);
          const bf16x8 kl = *(const bf16x8*)(&sKl[cur][ko]);
          a = MFMA(kh, fqh[c], a);
          a = MFMA(kl, fqh[c], a);
          a = MFMA(kh, fql[c], a);
        }
        s[blk] = a;
      } else {
        s[blk] = f32x4{-1e30f, -1e30f, -1e30f, -1e30f};
      }
    }
    __builtin_amdgcn_s_setprio(0);

    if (kvt == qt) {  // element-wise causal mask: k > q
#pragma unroll
      for (int blk = 0; blk < 4; ++blk)
#pragma unroll
        for (int r = 0; r < 4; ++r) {
          const int k = kv0 + blk * 16 + q4 * 4 + r;
          if (k > qg) s[blk][r] = -1e30f;
        }
    }

    // lane-local online softmax for q=qg (duplicated across the 4 q4 lanes)
    const float m0 = fmaxf(fmaxf(s[0][0], s[0][1]), fmaxf(s[0][2], s[0][3]));
    const float m1 = fmaxf(fmaxf(s[1][0], s[1][1]), fmaxf(s[1][2], s[1][3]));
    const float m2 = fmaxf(fmaxf(s[2][0], s[2][1]), fmaxf(s[2][2], s[2][3]));
    const float m3 = fmaxf(fmaxf(s[3][0], s[3][1]), fmaxf(s[3][2], s[3][3]));
    float mx = fmaxf(fmaxf(m0, m1), fmaxf(m2, m3));
    mx = fmaxf(mx, __shfl_xor(mx, 16, 64));
    mx = fmaxf(mx, __shfl_xor(mx, 32, 64));

    // defer-max (T13): only rescale when the tile max grew materially.
    // While deferred, P <= 2^8 (bf16/f32 headroom fine).
    if (__any(mx - mrun > DEFER)) {
      const float mnew = fmaxf(mrun, mx);
      const float scale = EXP2F((mrun - mnew) * SC);
      mrun = mnew;
      lrun *= scale;
#pragma unroll
      for (int d = 0; d < 4; ++d) accT[d] *= scale;
    }
    const float mn2 = mrun * SC;

    float ps = 0.f;
#pragma unroll
    for (int blk = 0; blk < 4; ++blk)
#pragma unroll
      for (int rp = 0; rp < 2; ++rp) {
        const float p0 = EXP2F(__builtin_fmaf(s[blk][2 * rp], SC, -mn2));
        const float p1 = EXP2F(__builtin_fmaf(s[blk][2 * rp + 1], SC, -mn2));
        ps += p0 + p1;
        bf16x2 w;
        w[0] = (__bf16)p0;
        w[1] = (__bf16)p1;
        *(bf16x2*)(&sP[wid][r16 * 72 + blk * 16 + q4 * 4 + 2 * rp]) = w;
      }
    ps += __shfl_xor(ps, 16, 64);
    ps += __shfl_xor(ps, 32, 64);
    lrun += ps;

    asm volatile("s_waitcnt lgkmcnt(0)" ::: "memory");  // sP visible to own wave
    __builtin_amdgcn_sched_barrier(0);

    // O^T += V^T P : A = V^T rows (row=l&15=d), B = P (col=l&15=q, row=k)
    __builtin_amdgcn_s_setprio(1);
#pragma unroll
    for (int c = 0; c < 2; ++c) {
      const bf16x8 pb = *(const bf16x8*)(&sP[wid][r16 * 72 + c * 32 + q4 * 8]);
#pragma unroll
      for (int d = 0; d < 4; ++d) {
        const bf16x8 va =
            *(const bf16x8*)(&sVt[cur][(d * 16 + r16) * 72 + c * 32 + q4 * 8]);
        accT[d] = MFMA(va, pb, accT[d]);
      }
    }
    __builtin_amdgcn_s_setprio(0);

    if (kvt < qt) {  // stage tile kvt+1 into the other buffer; refill st
      asm volatile("s_waitcnt vmcnt(0)" ::: "memory");
      WRITE(cur ^ 1);
      if (kvt + 1 < qt) ISSUE(kvt + 2);
    }
    asm volatile("s_waitcnt lgkmcnt(0)" ::: "memory");  // ds reads+writes done
    __builtin_amdgcn_sched_barrier(0);
    __builtin_amdgcn_s_barrier();  // single barrier per tile (no vmcnt drain)
    __builtin_amdgcn_sched_barrier(0);
  }

  const float rl = 1.0f / lrun;
#pragma unroll
  for (int d = 0; d < 4; ++d)
#pragma unroll
    for (int r = 0; r < 4; ++r)
      out[(size_t)qg * DOUT + h * 64 + d * 16 + q4 * 4 + r] = accT[d][r] * rl;
}

// ---------------- launch ----------------
extern "C" void kernel_launch(void* const* d_in, const int* in_sizes, int n_in,
                              void* d_out, int out_size, void* d_ws, size_t ws_size,
                              hipStream_t stream) {
  const float* x  = (const float*)d_in[0];
  const float* Wq = (const float*)d_in[1];
  const float* Wk = (const float*)d_in[2];
  const float* Wv = (const float*)d_in[3];
  char* ws = (char*)d_ws;

  // (T*DIN + 3*DOUT*DIN)/4 element-groups = 1310720 -> 5120 blocks
  split_all<<<5120, 256, 0, stream>>>(x, Wq, Wk, Wv, ws);
  qkv_proj<<<384, 256, 0, stream>>>(ws);
  attn_kernel<<<512, 256, 0, stream>>>(ws, (float*)d_out);
}